// Round 6
// baseline (80.821 us; speedup 1.0000x reference)
//
#include <hip/hip_runtime.h>

// (B,N,F) = (8, 4096, 256), fp32 in/out. out = (B, 5, F).
constexpr int B = 8;
constexpr int N = 4096;
constexpr int F = 256;
constexpr int F4 = F / 4;            // 64 float4 per row
constexpr int CHUNKS = 128;          // blocks per batch
constexpr int RPC = N / CHUNKS;      // 32 rows per block
constexpr int RPW = RPC / 4;         // 8 rows per wave
constexpr int L1R = 8;               // level-1 reducer blocks per batch
constexpr int PER_L1 = CHUNKS / L1R; // 16 partials per reducer

// Monotone float->uint mapping: f<g  <=>  sortable(f)<sortable(g)
__device__ __forceinline__ unsigned sortable_f32(float f) {
    unsigned u = __float_as_uint(f);
    return (u & 0x80000000u) ? ~u : (u | 0x80000000u);
}

__device__ __forceinline__ float agent_load(const float* p) {
    return __hip_atomic_load(p, __ATOMIC_RELAXED, __HIP_MEMORY_SCOPE_AGENT);
}
__device__ __forceinline__ void agent_store(float* p, float v) {
    __hip_atomic_store(p, v, __ATOMIC_RELAXED, __HIP_MEMORY_SCOPE_AGENT);
}

// Per-batch fence-FREE barrier (no buffer_wbl2/inv — that was the 199us pathology).
// vmcnt(0) acks all prior sc1/atomic traffic at the coherence point; readers use
// agent-scope loads that bypass stale caches. Co-residency: grid = 1024 blocks =
// 4/CU * 256 CU exactly (LDS ~38.5KB -> 4 fit; VGPR capped 128; 16 waves/CU <= 32).
__device__ __forceinline__ void fencefree_barrier(int* c) {
    asm volatile("s_waitcnt vmcnt(0)" ::: "memory");
    __syncthreads();
    if (threadIdx.x == 0) {
        __hip_atomic_fetch_add(c, 1, __ATOMIC_RELAXED, __HIP_MEMORY_SCOPE_AGENT);
        while (__hip_atomic_load(c, __ATOMIC_RELAXED, __HIP_MEMORY_SCOPE_AGENT) < CHUNKS)
            __builtin_amdgcn_s_sleep(2);
    }
    __syncthreads();
}

__global__ void __launch_bounds__(256, 4)
fused(const float* __restrict__ ref_rgb, const float* __restrict__ ref_flow,
      const float* __restrict__ sup_rgb, const float* __restrict__ sup_flow,
      float* __restrict__ out, int* __restrict__ cntbase,
      unsigned long long* __restrict__ minbase, unsigned long long* __restrict__ maxbase,
      float* __restrict__ partial, float* __restrict__ partial2) {
    const int b = blockIdx.x, chunk = blockIdx.y;
    const int t = threadIdx.x;           // 256 threads
    const int wave = t >> 6, lane = t & 63;

    __shared__ float4 supLds[RPC][F4];   // 32 KB: sup_flow rows staged A -> C
    __shared__ float4 red[4][F4];        // 4 KB
    __shared__ float  S[F];
    __shared__ float  Tv[F];
    __shared__ float  scoreS[RPC];
    __shared__ int    chosen[3];
    __shared__ int    lastFlag;

    int* cnt0 = cntbase + (0 * B + b) * 32;   // 128B-strided counters
    int* cnt1 = cntbase + (1 * B + b) * 32;
    int* cnt2 = cntbase + (2 * B + b) * 32;
    int* cnt3 = cntbase + (3 * B + b) * 32;
    unsigned long long* minslot = minbase + (size_t)b * 16;  // 3 slots, memset 0
    unsigned long long* maxslot = maxbase + (size_t)b * 16;  // 2 slots, memset 0

    // ---------- Phase A: ref column partials + stage sup rows to LDS (streams overlap) ----------
    const float4* rbase = reinterpret_cast<const float4*>(ref_flow)
                        + ((size_t)b * N + (size_t)chunk * RPC) * F4;
    const float4* sbase = reinterpret_cast<const float4*>(sup_flow)
                        + ((size_t)b * N + (size_t)chunk * RPC) * F4;
    float4 acc = make_float4(0.f, 0.f, 0.f, 0.f);
    #pragma unroll
    for (int i = 0; i < RPW; ++i) {
        float4 v = rbase[(size_t)(wave + 4 * i) * F4 + lane];
        acc.x += v.x; acc.y += v.y; acc.z += v.z; acc.w += v.w;
    }
    #pragma unroll
    for (int i = 0; i < RPW; ++i) {
        const int r = wave + 4 * i;
        supLds[r][lane] = sbase[(size_t)r * F4 + lane];   // global->VGPR->LDS
    }

    red[wave][lane] = acc;
    __syncthreads();
    if (wave == 0) {
        float4 a0 = red[0][lane], a1 = red[1][lane], a2 = red[2][lane], a3 = red[3][lane];
        float* pdst = partial + ((size_t)b * CHUNKS + chunk) * F + 4 * lane;
        agent_store(pdst + 0, a0.x + a1.x + a2.x + a3.x);
        agent_store(pdst + 1, a0.y + a1.y + a2.y + a3.y);
        agent_store(pdst + 2, a0.z + a1.z + a2.z + a3.z);
        agent_store(pdst + 3, a0.w + a1.w + a2.w + a3.w);
    }

    fencefree_barrier(cnt0);

    // ---------- Level-1 partial reduce: 8 blocks/batch fold 16 partials each ----------
    if (chunk < L1R) {
        float a = 0.f;
        const float* pb = partial + ((size_t)b * CHUNKS + chunk * PER_L1) * F + t;
        #pragma unroll 4
        for (int p = 0; p < PER_L1; ++p) a += agent_load(pb + (size_t)p * F);
        agent_store(partial2 + ((size_t)b * L1R + chunk) * F + t, a);
    }

    fencefree_barrier(cnt1);

    // ---------- Phase B: S = sum of 8 partial2 (redundant), ref dots (L2/L3 re-read), top-3 min ----------
    {
        float sacc = 0.f;
        #pragma unroll
        for (int q = 0; q < L1R; ++q)
            sacc += agent_load(partial2 + ((size_t)b * L1R + q) * F + t);
        S[t] = sacc;
        __syncthreads();

        float4 s4 = reinterpret_cast<const float4*>(S)[lane];
        #pragma unroll
        for (int i = 0; i < RPW; ++i) {
            const int r = wave + 4 * i;
            float4 a = rbase[(size_t)r * F4 + lane];
            float d = a.x * s4.x + a.y * s4.y + a.z * s4.z + a.w * s4.w;
            #pragma unroll
            for (int off = 32; off; off >>= 1) d += __shfl_xor(d, off);
            if (lane == 0) scoreS[r] = d;
        }
        __syncthreads();

        if (wave == 0) {
            // inv = ~packed: larger inv == smaller (score, idx). Lanes >= RPC: worst sentinel.
            const unsigned gidx = (unsigned)(chunk * RPC + lane);
            unsigned long long inv = 0;
            if (lane < RPC)
                inv = ~((((unsigned long long)sortable_f32(scoreS[lane])) << 32) | (unsigned long long)gidx);
            unsigned long long cur = inv;
            for (int k = 0; k < 3; ++k) {
                unsigned long long m = cur;
                #pragma unroll
                for (int off = 32; off; off >>= 1) {
                    unsigned long long o = __shfl_xor(m, off);
                    if (o > m) m = o;
                }
                if (lane == 0) {
                    unsigned long long x = m;   // lock-free bubbling insert (exact top-3)
                    #pragma unroll
                    for (int s = 0; s < 3; ++s) {
                        unsigned long long old = atomicMax(&minslot[s], x);
                        x = (old < x) ? old : x;
                    }
                }
                if (cur == m) cur = 0;
            }
        }
    }

    fencefree_barrier(cnt2);

    // ---------- Phase C: decode top-3, Tv, rows 0-2, sup dots (LDS), top-2 max ----------
    if (t == 0) {
        unsigned long long y0 = __hip_atomic_load(&minslot[0], __ATOMIC_RELAXED, __HIP_MEMORY_SCOPE_AGENT);
        unsigned long long y1 = __hip_atomic_load(&minslot[1], __ATOMIC_RELAXED, __HIP_MEMORY_SCOPE_AGENT);
        unsigned long long y2 = __hip_atomic_load(&minslot[2], __ATOMIC_RELAXED, __HIP_MEMORY_SCOPE_AGENT);
        unsigned long long tmp;
        if (y1 > y0) { tmp = y0; y0 = y1; y1 = tmp; }
        if (y2 > y0) { tmp = y0; y0 = y2; y2 = tmp; }
        if (y2 > y1) { tmp = y1; y1 = y2; y2 = tmp; }
        chosen[0] = (int)((~y0) & 0xFFFFFFFFull);
        chosen[1] = (int)((~y1) & 0xFFFFFFFFull);
        chosen[2] = (int)((~y2) & 0xFFFFFFFFull);
    }
    __syncthreads();
    {
        const int i0 = chosen[0], i1 = chosen[1], i2 = chosen[2];
        Tv[t] = ref_flow[((size_t)b * N + i0) * F + t]
              + ref_flow[((size_t)b * N + i1) * F + t]
              + ref_flow[((size_t)b * N + i2) * F + t];
        if (chunk == 0) {
            out[((size_t)b * 5 + 0) * F + t] = ref_rgb[((size_t)b * N + i0) * F + t];
            out[((size_t)b * 5 + 1) * F + t] = ref_rgb[((size_t)b * N + i1) * F + t];
            out[((size_t)b * 5 + 2) * F + t] = ref_rgb[((size_t)b * N + i2) * F + t];
        }
    }
    __syncthreads();
    {
        float4 tv4 = reinterpret_cast<const float4*>(Tv)[lane];
        #pragma unroll
        for (int i = 0; i < RPW; ++i) {
            const int r = wave + 4 * i;
            float4 a = supLds[r][lane];
            float d = a.x * tv4.x + a.y * tv4.y + a.z * tv4.z + a.w * tv4.w;
            #pragma unroll
            for (int off = 32; off; off >>= 1) d += __shfl_xor(d, off);
            if (lane == 0) scoreS[r] = d;
        }
        __syncthreads();

        if (wave == 0) {
            // packed: larger == larger score, tie -> smaller index. Lanes >= RPC: 0 sentinel.
            const unsigned gidx = (unsigned)(chunk * RPC + lane);
            unsigned long long pk = 0;
            if (lane < RPC)
                pk = (((unsigned long long)sortable_f32(scoreS[lane])) << 32) |
                     (unsigned long long)(0xFFFFFFFFu - gidx);
            unsigned long long cur = pk;
            for (int k = 0; k < 2; ++k) {
                unsigned long long m = cur;
                #pragma unroll
                for (int off = 32; off; off >>= 1) {
                    unsigned long long o = __shfl_xor(m, off);
                    if (o > m) m = o;
                }
                if (lane == 0) {
                    unsigned long long x = m;
                    #pragma unroll
                    for (int s = 0; s < 2; ++s) {
                        unsigned long long old = atomicMax(&maxslot[s], x);
                        x = (old < x) ? old : x;
                    }
                }
                if (cur == m) cur = 0;
            }
        }
    }

    // ---------- Phase D: last arriver per batch (no spin) merges + gathers rows 3-4 ----------
    asm volatile("s_waitcnt vmcnt(0)" ::: "memory");
    __syncthreads();
    if (t == 0) {
        int old = __hip_atomic_fetch_add(cnt3, 1, __ATOMIC_RELAXED, __HIP_MEMORY_SCOPE_AGENT);
        lastFlag = (old == CHUNKS - 1);
    }
    __syncthreads();
    if (lastFlag) {
        if (t == 0) {
            unsigned long long y0 = __hip_atomic_load(&maxslot[0], __ATOMIC_RELAXED, __HIP_MEMORY_SCOPE_AGENT);
            unsigned long long y1 = __hip_atomic_load(&maxslot[1], __ATOMIC_RELAXED, __HIP_MEMORY_SCOPE_AGENT);
            if (y1 > y0) { unsigned long long tmp = y0; y0 = y1; y1 = tmp; }
            chosen[0] = (int)(0xFFFFFFFFu - (unsigned)(y0 & 0xFFFFFFFFull));
            chosen[1] = (int)(0xFFFFFFFFu - (unsigned)(y1 & 0xFFFFFFFFull));
        }
        __syncthreads();
        out[((size_t)b * 5 + 3) * F + t] = sup_rgb[((size_t)b * N + chosen[0]) * F + t];
        out[((size_t)b * 5 + 4) * F + t] = sup_rgb[((size_t)b * N + chosen[1]) * F + t];
    }
}

extern "C" void kernel_launch(void* const* d_in, const int* in_sizes, int n_in,
                              void* d_out, int out_size, void* d_ws, size_t ws_size,
                              hipStream_t stream) {
    const float* ref_rgb  = (const float*)d_in[0];
    const float* ref_flow = (const float*)d_in[1];
    const float* sup_rgb  = (const float*)d_in[2];
    const float* sup_flow = (const float*)d_in[3];
    float* out = (float*)d_out;

    // ws: [0,4096) counters (4 barriers x 8 batches x 128B) | [4096,5120) minslots |
    //     [8192,9216) maxslots | [16384, +1MB) partial | then partial2 (8KB)
    int* cntbase = (int*)d_ws;
    unsigned long long* minbase = (unsigned long long*)((char*)d_ws + 4096);
    unsigned long long* maxbase = (unsigned long long*)((char*)d_ws + 8192);
    float* partial  = (float*)((char*)d_ws + 16384);
    float* partial2 = partial + (size_t)B * CHUNKS * F;

    hipMemsetAsync(d_ws, 0, 16384, stream);  // re-init sync state every call (replay-safe)
    fused<<<dim3(B, CHUNKS), 256, 0, stream>>>(ref_rgb, ref_flow, sup_rgb, sup_flow,
                                               out, cntbase, minbase, maxbase, partial, partial2);
}

// Round 7
// 56.345 us; speedup vs baseline: 1.4344x; 1.4344x over previous
//
#include <hip/hip_runtime.h>

// (B,N,F) = (8, 4096, 256), fp32 in/out. out = (B, 5, F).
constexpr int B = 8;
constexpr int N = 4096;
constexpr int F = 256;
constexpr int F4 = F / 4;        // 64 float4 per row
constexpr int CHUNKS = 64;       // blocks per batch
constexpr int RPC = N / CHUNKS;  // 64 rows per block
constexpr int RPW = RPC / 4;     // 16 rows per wave

// Monotone float->uint mapping: f<g  <=>  sortable(f)<sortable(g)
__device__ __forceinline__ unsigned sortable_f32(float f) {
    unsigned u = __float_as_uint(f);
    return (u & 0x80000000u) ? ~u : (u | 0x80000000u);
}

__device__ __forceinline__ float agent_load(const float* p) {
    return __hip_atomic_load(p, __ATOMIC_RELAXED, __HIP_MEMORY_SCOPE_AGENT);
}
__device__ __forceinline__ void agent_store(float* p, float v) {
    __hip_atomic_store(p, v, __ATOMIC_RELAXED, __HIP_MEMORY_SCOPE_AGENT);
}

// Direct global->LDS copy, 16B per lane, zero VGPR destination cost.
// LDS dest is wave-uniform base + lane*16 (HW rule); global src is per-lane.
__device__ __forceinline__ void gload_lds16(const float4* gsrc, float4* ldst) {
    __builtin_amdgcn_global_load_lds(
        (const __attribute__((address_space(1))) void*)gsrc,
        (__attribute__((address_space(3))) void*)ldst,
        16, 0, 0);
}

// Per-batch fence-FREE barrier (no buffer_wbl2/inv — that was the 199us pathology).
// vmcnt(0) acks all prior global traffic (incl. global_load_lds) at the coherence
// point; readers use agent-scope loads. Co-residency: grid = 512 = 2/CU * 256 CU
// (LDS ~70KB -> exactly 2 blocks/CU; launch_bounds(256,2)) => no spin deadlock.
__device__ __forceinline__ void fencefree_barrier(int* c) {
    asm volatile("s_waitcnt vmcnt(0)" ::: "memory");
    __syncthreads();
    if (threadIdx.x == 0) {
        __hip_atomic_fetch_add(c, 1, __ATOMIC_RELAXED, __HIP_MEMORY_SCOPE_AGENT);
        while (__hip_atomic_load(c, __ATOMIC_RELAXED, __HIP_MEMORY_SCOPE_AGENT) < CHUNKS)
            __builtin_amdgcn_s_sleep(8);
    }
    __syncthreads();
}

__global__ void __launch_bounds__(256, 2)
fused(const float* __restrict__ ref_rgb, const float* __restrict__ ref_flow,
      const float* __restrict__ sup_rgb, const float* __restrict__ sup_flow,
      float* __restrict__ out, int* __restrict__ cntbase,
      unsigned long long* __restrict__ minbase, unsigned long long* __restrict__ maxbase,
      float* __restrict__ partial) {
    const int b = blockIdx.x, chunk = blockIdx.y;
    const int t = threadIdx.x;           // 256 threads
    const int wave = t >> 6, lane = t & 63;
    const int w16 = wave * RPW;          // this wave's first local row

    __shared__ float4 supLds[RPC][F4];   // 64 KB: sup_flow rows, staged A -> used C
    __shared__ float4 red[4][F4];        // 4 KB
    __shared__ float  S[F];
    __shared__ float  Tv[F];
    __shared__ float  scoreS[RPC];
    __shared__ int    chosen[3];
    __shared__ int    lastFlag;

    int* cnt0 = cntbase + (0 * B + b) * 32;   // 128B-strided counters
    int* cnt1 = cntbase + (1 * B + b) * 32;
    int* cnt2 = cntbase + (2 * B + b) * 32;
    unsigned long long* minslot = minbase + (size_t)b * 16;  // 3 slots, memset 0
    unsigned long long* maxslot = maxbase + (size_t)b * 16;  // 2 slots, memset 0

    const float4* rbase = reinterpret_cast<const float4*>(ref_flow)
                        + ((size_t)b * N + (size_t)chunk * RPC) * F4;
    const float4* sbase = reinterpret_cast<const float4*>(sup_flow)
                        + ((size_t)b * N + (size_t)chunk * RPC) * F4;

    // ---------- Phase A: overlap BOTH 32MB streams at high concurrency ----------
    // sup rows -> LDS via global_load_lds (no VGPR destinations, 16 in flight/thread)
    #pragma unroll
    for (int i = 0; i < RPW; ++i)
        gload_lds16(sbase + (size_t)(w16 + i) * F4 + lane, &supLds[w16 + i][0]);

    // ref rows -> v[16] (64 VGPRs of destinations, all loads issued before any use)
    float4 v[RPW];
    #pragma unroll
    for (int i = 0; i < RPW; ++i)
        v[i] = rbase[(size_t)(w16 + i) * F4 + lane];

    float4 acc = make_float4(0.f, 0.f, 0.f, 0.f);
    #pragma unroll
    for (int i = 0; i < RPW; ++i) {
        acc.x += v[i].x; acc.y += v[i].y; acc.z += v[i].z; acc.w += v[i].w;
    }
    red[wave][lane] = acc;
    __syncthreads();
    if (wave == 0) {
        float4 a0 = red[0][lane], a1 = red[1][lane], a2 = red[2][lane], a3 = red[3][lane];
        float* pdst = partial + ((size_t)b * CHUNKS + chunk) * F + 4 * lane;
        agent_store(pdst + 0, a0.x + a1.x + a2.x + a3.x);
        agent_store(pdst + 1, a0.y + a1.y + a2.y + a3.y);
        agent_store(pdst + 2, a0.z + a1.z + a2.z + a3.z);
        agent_store(pdst + 3, a0.w + a1.w + a2.w + a3.w);
    }

    fencefree_barrier(cnt0);   // drains gload_lds into supLds too

    // ---------- Phase B: S = sum partials (redundant), ref dots (L2/L3 re-read), top-3 min ----------
    {
        float sacc = 0.f;
        const float* pb = partial + (size_t)b * CHUNKS * F + t;
        #pragma unroll 8
        for (int p = 0; p < CHUNKS; ++p) sacc += agent_load(pb + (size_t)p * F);
        S[t] = sacc;
        __syncthreads();

        float4 s4 = reinterpret_cast<const float4*>(S)[lane];
        #pragma unroll
        for (int i = 0; i < RPW; ++i) {
            const int r = w16 + i;
            float4 a = rbase[(size_t)r * F4 + lane];   // re-read: L2/L3 hit
            float d = a.x * s4.x + a.y * s4.y + a.z * s4.z + a.w * s4.w;
            #pragma unroll
            for (int off = 32; off; off >>= 1) d += __shfl_xor(d, off);
            if (lane == 0) scoreS[r] = d;
        }
        __syncthreads();

        if (wave == 0) {
            // inv = ~packed: larger inv == smaller (score, idx). RPC == 64 == lanes.
            const unsigned gidx = (unsigned)(chunk * RPC + lane);
            unsigned long long inv =
                ~((((unsigned long long)sortable_f32(scoreS[lane])) << 32) | (unsigned long long)gidx);
            unsigned long long cur = inv;
            for (int k = 0; k < 3; ++k) {
                unsigned long long m = cur;
                #pragma unroll
                for (int off = 32; off; off >>= 1) {
                    unsigned long long o = __shfl_xor(m, off);
                    if (o > m) m = o;
                }
                if (lane == 0) {
                    unsigned long long x = m;   // lock-free bubbling insert (exact top-3)
                    #pragma unroll
                    for (int s = 0; s < 3; ++s) {
                        unsigned long long old = atomicMax(&minslot[s], x);
                        x = (old < x) ? old : x;
                    }
                }
                if (cur == m) cur = 0;
            }
        }
    }

    fencefree_barrier(cnt1);

    // ---------- Phase C: decode top-3, Tv, rows 0-2, sup dots (LDS), top-2 max ----------
    if (t == 0) {
        unsigned long long y0 = __hip_atomic_load(&minslot[0], __ATOMIC_RELAXED, __HIP_MEMORY_SCOPE_AGENT);
        unsigned long long y1 = __hip_atomic_load(&minslot[1], __ATOMIC_RELAXED, __HIP_MEMORY_SCOPE_AGENT);
        unsigned long long y2 = __hip_atomic_load(&minslot[2], __ATOMIC_RELAXED, __HIP_MEMORY_SCOPE_AGENT);
        unsigned long long tmp;
        if (y1 > y0) { tmp = y0; y0 = y1; y1 = tmp; }
        if (y2 > y0) { tmp = y0; y0 = y2; y2 = tmp; }
        if (y2 > y1) { tmp = y1; y1 = y2; y2 = tmp; }
        chosen[0] = (int)((~y0) & 0xFFFFFFFFull);
        chosen[1] = (int)((~y1) & 0xFFFFFFFFull);
        chosen[2] = (int)((~y2) & 0xFFFFFFFFull);
    }
    __syncthreads();
    {
        const int i0 = chosen[0], i1 = chosen[1], i2 = chosen[2];
        Tv[t] = ref_flow[((size_t)b * N + i0) * F + t]      // read-only input: cache-safe
              + ref_flow[((size_t)b * N + i1) * F + t]
              + ref_flow[((size_t)b * N + i2) * F + t];
        if (chunk == 0) {
            out[((size_t)b * 5 + 0) * F + t] = ref_rgb[((size_t)b * N + i0) * F + t];
            out[((size_t)b * 5 + 1) * F + t] = ref_rgb[((size_t)b * N + i1) * F + t];
            out[((size_t)b * 5 + 2) * F + t] = ref_rgb[((size_t)b * N + i2) * F + t];
        }
    }
    __syncthreads();
    {
        float4 tv4 = reinterpret_cast<const float4*>(Tv)[lane];
        #pragma unroll
        for (int i = 0; i < RPW; ++i) {
            const int r = w16 + i;
            float4 a = supLds[r][lane];                     // LDS, conflict-free
            float d = a.x * tv4.x + a.y * tv4.y + a.z * tv4.z + a.w * tv4.w;
            #pragma unroll
            for (int off = 32; off; off >>= 1) d += __shfl_xor(d, off);
            if (lane == 0) scoreS[r] = d;
        }
        __syncthreads();

        if (wave == 0) {
            // packed: larger == larger score, tie -> smaller index
            const unsigned gidx = (unsigned)(chunk * RPC + lane);
            unsigned long long pk =
                (((unsigned long long)sortable_f32(scoreS[lane])) << 32) |
                (unsigned long long)(0xFFFFFFFFu - gidx);
            unsigned long long cur = pk;
            for (int k = 0; k < 2; ++k) {
                unsigned long long m = cur;
                #pragma unroll
                for (int off = 32; off; off >>= 1) {
                    unsigned long long o = __shfl_xor(m, off);
                    if (o > m) m = o;
                }
                if (lane == 0) {
                    unsigned long long x = m;
                    #pragma unroll
                    for (int s = 0; s < 2; ++s) {
                        unsigned long long old = atomicMax(&maxslot[s], x);
                        x = (old < x) ? old : x;
                    }
                }
                if (cur == m) cur = 0;
            }
        }
    }

    // ---------- Phase D: last arriver per batch (no spin) merges + gathers rows 3-4 ----------
    asm volatile("s_waitcnt vmcnt(0)" ::: "memory");
    __syncthreads();
    if (t == 0) {
        int old = __hip_atomic_fetch_add(cnt2, 1, __ATOMIC_RELAXED, __HIP_MEMORY_SCOPE_AGENT);
        lastFlag = (old == CHUNKS - 1);
    }
    __syncthreads();
    if (lastFlag) {
        if (t == 0) {
            unsigned long long y0 = __hip_atomic_load(&maxslot[0], __ATOMIC_RELAXED, __HIP_MEMORY_SCOPE_AGENT);
            unsigned long long y1 = __hip_atomic_load(&maxslot[1], __ATOMIC_RELAXED, __HIP_MEMORY_SCOPE_AGENT);
            if (y1 > y0) { unsigned long long tmp = y0; y0 = y1; y1 = tmp; }
            chosen[0] = (int)(0xFFFFFFFFu - (unsigned)(y0 & 0xFFFFFFFFull));
            chosen[1] = (int)(0xFFFFFFFFu - (unsigned)(y1 & 0xFFFFFFFFull));
        }
        __syncthreads();
        out[((size_t)b * 5 + 3) * F + t] = sup_rgb[((size_t)b * N + chosen[0]) * F + t];
        out[((size_t)b * 5 + 4) * F + t] = sup_rgb[((size_t)b * N + chosen[1]) * F + t];
    }
}

extern "C" void kernel_launch(void* const* d_in, const int* in_sizes, int n_in,
                              void* d_out, int out_size, void* d_ws, size_t ws_size,
                              hipStream_t stream) {
    const float* ref_rgb  = (const float*)d_in[0];
    const float* ref_flow = (const float*)d_in[1];
    const float* sup_rgb  = (const float*)d_in[2];
    const float* sup_flow = (const float*)d_in[3];
    float* out = (float*)d_out;

    // ws: [0,3072) counters | [4096,5120) minslots | [8192,9216) maxslots | [16384,...) partial
    int* cntbase = (int*)d_ws;
    unsigned long long* minbase = (unsigned long long*)((char*)d_ws + 4096);
    unsigned long long* maxbase = (unsigned long long*)((char*)d_ws + 8192);
    float* partial = (float*)((char*)d_ws + 16384);

    hipMemsetAsync(d_ws, 0, 16384, stream);  // re-init sync state every call (replay-safe)
    fused<<<dim3(B, CHUNKS), 256, 0, stream>>>(ref_rgb, ref_flow, sup_rgb, sup_flow,
                                               out, cntbase, minbase, maxbase, partial);
}

// Round 8
// 41.424 us; speedup vs baseline: 1.9510x; 1.3602x over previous
//
#include <hip/hip_runtime.h>

// (B,N,F) = (8, 4096, 256), fp32 in/out. out = (B, 5, F).
constexpr int B = 8;
constexpr int N = 4096;
constexpr int F = 256;
constexpr int F4 = F / 4;        // 64 float4 per row
constexpr int CH1 = 64;          // K1/K2 chunks per batch
constexpr int R1 = N / CH1;      // 64 rows per block
constexpr int W1 = R1 / 4;       // 16 rows per wave
constexpr int CH3 = 128;         // K3 chunks per batch
constexpr int R3 = N / CH3;      // 32 rows per block
constexpr int W3 = R3 / 4;       // 8 rows per wave

// Monotone float->uint mapping: f<g  <=>  sortable(f)<sortable(g)
__device__ __forceinline__ unsigned sortable_f32(float f) {
    unsigned u = __float_as_uint(f);
    return (u & 0x80000000u) ? ~u : (u | 0x80000000u);
}

__device__ __forceinline__ unsigned long long agent_load_u64(const unsigned long long* p) {
    return __hip_atomic_load(p, __ATOMIC_RELAXED, __HIP_MEMORY_SCOPE_AGENT);
}

// ---------------- K1: column partials of ref_flow + zero-init sync state ----------------
__global__ void k1_colsum(const float* __restrict__ ref_flow, float* __restrict__ partial,
                          int* __restrict__ cnt, unsigned long long* __restrict__ minbase,
                          unsigned long long* __restrict__ maxbase) {
    const int b = blockIdx.x, chunk = blockIdx.y;
    const int t = threadIdx.x, wave = t >> 6, lane = t & 63;
    const int w16 = wave * W1;
    __shared__ float4 red[4][F4];

    const float4* rbase = reinterpret_cast<const float4*>(ref_flow)
                        + ((size_t)b * N + (size_t)chunk * R1) * F4;
    float4 v[W1];
    #pragma unroll
    for (int i = 0; i < W1; ++i) v[i] = rbase[(size_t)(w16 + i) * F4 + lane];

    float4 acc = make_float4(0.f, 0.f, 0.f, 0.f);
    #pragma unroll
    for (int i = 0; i < W1; ++i) {
        acc.x += v[i].x; acc.y += v[i].y; acc.z += v[i].z; acc.w += v[i].w;
    }
    red[wave][lane] = acc;
    __syncthreads();
    if (wave == 0) {
        float4 a0 = red[0][lane], a1 = red[1][lane], a2 = red[2][lane], a3 = red[3][lane];
        float4 s = make_float4(a0.x + a1.x + a2.x + a3.x, a0.y + a1.y + a2.y + a3.y,
                               a0.z + a1.z + a2.z + a3.z, a0.w + a1.w + a2.w + a3.w);
        reinterpret_cast<float4*>(partial)[((size_t)b * CH1 + chunk) * F4 + lane] = s;
    }
    // zero-init per-batch slots/counters (visible to K2/K3 via kernel boundary)
    if (chunk == 0) {
        if (t < 3) minbase[(size_t)b * 16 + t] = 0ull;
        if (t < 2) maxbase[(size_t)b * 16 + t] = 0ull;
        if (t == 0) cnt[b * 32] = 0;
    }
}

// ---------------- K2: redundant S-reduce + ref dots (L2/L3) + wave top-3 min -> slots ----------------
__global__ void k2_dot1(const float* __restrict__ ref_flow, const float* __restrict__ partial,
                        unsigned long long* __restrict__ minbase) {
    const int b = blockIdx.x, chunk = blockIdx.y;
    const int t = threadIdx.x, wave = t >> 6, lane = t & 63;
    const int w16 = wave * W1;
    __shared__ float S[F];
    __shared__ float scoreS[R1];

    float sacc = 0.f;
    const float* pb = partial + (size_t)b * CH1 * F + t;
    #pragma unroll 8
    for (int p = 0; p < CH1; ++p) sacc += pb[(size_t)p * F];
    S[t] = sacc;
    __syncthreads();

    const float4* rbase = reinterpret_cast<const float4*>(ref_flow)
                        + ((size_t)b * N + (size_t)chunk * R1) * F4;
    float4 s4 = reinterpret_cast<const float4*>(S)[lane];
    float4 v[W1];
    #pragma unroll
    for (int i = 0; i < W1; ++i) v[i] = rbase[(size_t)(w16 + i) * F4 + lane];
    #pragma unroll
    for (int i = 0; i < W1; ++i) {
        float d = v[i].x * s4.x + v[i].y * s4.y + v[i].z * s4.z + v[i].w * s4.w;
        #pragma unroll
        for (int off = 32; off; off >>= 1) d += __shfl_xor(d, off);
        if (lane == 0) scoreS[w16 + i] = d;
    }
    __syncthreads();

    if (wave == 0) {
        unsigned long long* minslot = minbase + (size_t)b * 16;
        // inv = ~packed: larger inv == smaller (score, idx). R1 == 64 == lanes.
        const unsigned gidx = (unsigned)(chunk * R1 + lane);
        unsigned long long inv =
            ~((((unsigned long long)sortable_f32(scoreS[lane])) << 32) | (unsigned long long)gidx);
        unsigned long long cur = inv;
        for (int k = 0; k < 3; ++k) {
            unsigned long long m = cur;
            #pragma unroll
            for (int off = 32; off; off >>= 1) {
                unsigned long long o = __shfl_xor(m, off);
                if (o > m) m = o;
            }
            if (lane == 0) {
                unsigned long long x = m;   // lock-free bubbling insert: exact top-3
                #pragma unroll
                for (int s = 0; s < 3; ++s) {
                    unsigned long long old = atomicMax(&minslot[s], x);
                    x = (old < x) ? old : x;
                }
            }
            if (cur == m) cur = 0;
        }
    }
}

// ---------------- K3: decode top-3, Tv, rows 0-2, cold sup dots, top-2 max, last-arriver gather ----------------
__global__ void k3_dot2(const float* __restrict__ ref_rgb, const float* __restrict__ ref_flow,
                        const float* __restrict__ sup_rgb, const float* __restrict__ sup_flow,
                        float* __restrict__ out, const unsigned long long* __restrict__ minbase,
                        unsigned long long* __restrict__ maxbase, int* __restrict__ cnt) {
    const int b = blockIdx.x, chunk = blockIdx.y;
    const int t = threadIdx.x, wave = t >> 6, lane = t & 63;
    const int w8 = wave * W3;
    __shared__ float Tv[F];
    __shared__ float scoreS[R3];
    __shared__ int chosen[3];
    __shared__ int lastFlag;

    // issue the cold sup_flow loads first (stream overlaps decode/Tv build)
    const float4* sbase = reinterpret_cast<const float4*>(sup_flow)
                        + ((size_t)b * N + (size_t)chunk * R3) * F4;
    float4 v[W3];
    #pragma unroll
    for (int i = 0; i < W3; ++i) v[i] = sbase[(size_t)(w8 + i) * F4 + lane];

    // decode top-3 (plain loads: K2 finished at kernel boundary)
    if (t == 0) {
        unsigned long long y0 = minbase[(size_t)b * 16 + 0];
        unsigned long long y1 = minbase[(size_t)b * 16 + 1];
        unsigned long long y2 = minbase[(size_t)b * 16 + 2];
        unsigned long long tmp;
        if (y1 > y0) { tmp = y0; y0 = y1; y1 = tmp; }
        if (y2 > y0) { tmp = y0; y0 = y2; y2 = tmp; }
        if (y2 > y1) { tmp = y1; y1 = y2; y2 = tmp; }
        chosen[0] = (int)((~y0) & 0xFFFFFFFFull);
        chosen[1] = (int)((~y1) & 0xFFFFFFFFull);
        chosen[2] = (int)((~y2) & 0xFFFFFFFFull);
    }
    __syncthreads();
    {
        const int i0 = chosen[0], i1 = chosen[1], i2 = chosen[2];
        Tv[t] = ref_flow[((size_t)b * N + i0) * F + t]      // L3-resident
              + ref_flow[((size_t)b * N + i1) * F + t]
              + ref_flow[((size_t)b * N + i2) * F + t];
        if (chunk == 0) {
            out[((size_t)b * 5 + 0) * F + t] = ref_rgb[((size_t)b * N + i0) * F + t];
            out[((size_t)b * 5 + 1) * F + t] = ref_rgb[((size_t)b * N + i1) * F + t];
            out[((size_t)b * 5 + 2) * F + t] = ref_rgb[((size_t)b * N + i2) * F + t];
        }
    }
    __syncthreads();

    float4 tv4 = reinterpret_cast<const float4*>(Tv)[lane];
    #pragma unroll
    for (int i = 0; i < W3; ++i) {
        float d = v[i].x * tv4.x + v[i].y * tv4.y + v[i].z * tv4.z + v[i].w * tv4.w;
        #pragma unroll
        for (int off = 32; off; off >>= 1) d += __shfl_xor(d, off);
        if (lane == 0) scoreS[w8 + i] = d;
    }
    __syncthreads();

    if (wave == 0) {
        unsigned long long* maxslot = maxbase + (size_t)b * 16;
        // packed: larger == larger score, tie -> smaller index. lanes >= R3: worst sentinel 0.
        const unsigned gidx = (unsigned)(chunk * R3 + lane);
        unsigned long long pk = 0;
        if (lane < R3)
            pk = (((unsigned long long)sortable_f32(scoreS[lane])) << 32) |
                 (unsigned long long)(0xFFFFFFFFu - gidx);
        unsigned long long cur = pk;
        for (int k = 0; k < 2; ++k) {
            unsigned long long m = cur;
            #pragma unroll
            for (int off = 32; off; off >>= 1) {
                unsigned long long o = __shfl_xor(m, off);
                if (o > m) m = o;
            }
            if (lane == 0) {
                unsigned long long x = m;
                #pragma unroll
                for (int s = 0; s < 2; ++s) {
                    unsigned long long old = atomicMax(&maxslot[s], x);
                    x = (old < x) ? old : x;
                }
            }
            if (cur == m) cur = 0;
        }
    }

    // last arriver per batch gathers rows 3-4 (no spin; vmcnt(0) acks my atomics first)
    asm volatile("s_waitcnt vmcnt(0)" ::: "memory");
    __syncthreads();
    if (t == 0) {
        int old = __hip_atomic_fetch_add(cnt + b * 32, 1, __ATOMIC_RELAXED, __HIP_MEMORY_SCOPE_AGENT);
        lastFlag = (old == CH3 - 1);
    }
    __syncthreads();
    if (lastFlag) {
        if (t == 0) {
            unsigned long long y0 = agent_load_u64(maxbase + (size_t)b * 16 + 0);
            unsigned long long y1 = agent_load_u64(maxbase + (size_t)b * 16 + 1);
            if (y1 > y0) { unsigned long long tmp = y0; y0 = y1; y1 = tmp; }
            chosen[0] = (int)(0xFFFFFFFFu - (unsigned)(y0 & 0xFFFFFFFFull));
            chosen[1] = (int)(0xFFFFFFFFu - (unsigned)(y1 & 0xFFFFFFFFull));
        }
        __syncthreads();
        out[((size_t)b * 5 + 3) * F + t] = sup_rgb[((size_t)b * N + chosen[0]) * F + t];
        out[((size_t)b * 5 + 4) * F + t] = sup_rgb[((size_t)b * N + chosen[1]) * F + t];
    }
}

extern "C" void kernel_launch(void* const* d_in, const int* in_sizes, int n_in,
                              void* d_out, int out_size, void* d_ws, size_t ws_size,
                              hipStream_t stream) {
    const float* ref_rgb  = (const float*)d_in[0];
    const float* ref_flow = (const float*)d_in[1];
    const float* sup_rgb  = (const float*)d_in[2];
    const float* sup_flow = (const float*)d_in[3];
    float* out = (float*)d_out;

    // ws: [0,1024) counters (8 batches x 128B) | [4096,5120) minslots |
    //     [8192,9216) maxslots | [16384, +512KB) partial
    int* cnt = (int*)d_ws;
    unsigned long long* minbase = (unsigned long long*)((char*)d_ws + 4096);
    unsigned long long* maxbase = (unsigned long long*)((char*)d_ws + 8192);
    float* partial = (float*)((char*)d_ws + 16384);

    k1_colsum<<<dim3(B, CH1), 256, 0, stream>>>(ref_flow, partial, cnt, minbase, maxbase);
    k2_dot1<<<dim3(B, CH1), 256, 0, stream>>>(ref_flow, partial, minbase);
    k3_dot2<<<dim3(B, CH3), 256, 0, stream>>>(ref_rgb, ref_flow, sup_rgb, sup_flow,
                                              out, minbase, maxbase, cnt);
}